// Round 20
// baseline (182.594 us; speedup 1.0000x reference)
//
#include <hip/hip_runtime.h>
#include <hip/hip_bf16.h>
#include <math.h>
#include <stdint.h>

typedef __bf16 bf16;
typedef __bf16 bf16x8 __attribute__((ext_vector_type(8)));
typedef __bf16 bf16x4v __attribute__((ext_vector_type(4)));
typedef float f32x4 __attribute__((ext_vector_type(4)));

#define NHEADS 4
#define DM 768
#define DB 64
#define HD 192
#define BATCH 8
#define SEQ 1024
#define MROWS 8192
#define SCALE 0.07216878364870323f

__device__ __forceinline__ void gld_lds16(const void* g, void* l) {
  __builtin_amdgcn_global_load_lds(
      (__attribute__((address_space(1))) void*)(void*)g,
      (__attribute__((address_space(3))) void*)l, 16, 0, 0);
}

// ---------------- fused prologue: cvt Xd, cvt Xb, bias MLP, tiled weight transposes ----------------
__global__ __launch_bounds__(256) void prologue(
    const float* __restrict__ Xd, bf16* __restrict__ Xd_bf,
    const float* __restrict__ Xb, bf16* __restrict__ Xb_bf,
    const float* __restrict__ Wq, const float* __restrict__ Wv,
    const float* __restrict__ Wk, const float* __restrict__ Wo,
    bf16* __restrict__ WT0, bf16* __restrict__ WT1,
    bf16* __restrict__ WT2, bf16* __restrict__ WT3,
    const float* __restrict__ Wb1, const float* __restrict__ bb1,
    const float* __restrict__ Wb2, const float* __restrict__ bb2,
    float* __restrict__ biasarr) {
  __shared__ float Lt[64 * 65];
  const int id = blockIdx.x;
  const int tid = threadIdx.x;
  if (id < 6656) {
    const float* in = (id < 6144) ? Xd : Xb;
    bf16* out = (id < 6144) ? Xd_bf : Xb_bf;
    long i = (long)(id < 6144 ? id : id - 6144) * 256 + tid;
    f32x4 v = *(const f32x4*)&in[i * 4];
    bf16x4v t;
    t[0] = (bf16)v[0]; t[1] = (bf16)v[1]; t[2] = (bf16)v[2]; t[3] = (bf16)v[3];
    *(bf16x4v*)&out[i * 4] = t;
  } else if (id < 6688) {
    int idx = (id - 6656) * 256 + tid;
    const float* x = Xb + (long)idx * DB;
    float h[8];
#pragma unroll
    for (int j = 0; j < 8; ++j) h[j] = bb1[j];
    for (int k = 0; k < DB; ++k) {
      float xv = x[k];
#pragma unroll
      for (int j = 0; j < 8; ++j) h[j] = fmaf(xv, Wb1[k * 8 + j], h[j]);
    }
#pragma unroll
    for (int j = 0; j < 8; ++j) {
      float a = h[j];
      h[j] = 0.5f * a * (1.0f + erff(a * 0.7071067811865476f));
    }
    int b = idx >> 10, s = idx & 1023;
#pragma unroll
    for (int o = 0; o < 4; ++o) {
      float a = bb2[o];
#pragma unroll
      for (int j = 0; j < 8; ++j) a = fmaf(h[j], Wb2[j * 4 + o], a);
      biasarr[((long)(b * 4 + o) << 10) + s] = a;
    }
  } else {
    int wi = id - 6688;
    const float* W;
    bf16* WT;
    int K, tIdx;
    if (wi < 144)      { W = Wq; WT = WT0; K = DM; tIdx = wi; }
    else if (wi < 288) { W = Wv; WT = WT1; K = DM; tIdx = wi - 144; }
    else if (wi < 300) { W = Wk; WT = WT2; K = DB; tIdx = wi - 288; }
    else               { W = Wo; WT = WT3; K = DM; tIdx = wi - 300; }
    const int tk0 = (tIdx / 12) * 64;
    const int tn0 = (tIdx % 12) * 64;
#pragma unroll
    for (int p = 0; p < 4; ++p) {
      int r = p * 16 + (tid >> 4);
      int c = (tid & 15) * 4;
      f32x4 v = *(const f32x4*)&W[(long)(tk0 + r) * DM + tn0 + c];
      Lt[r * 65 + c] = v[0]; Lt[r * 65 + c + 1] = v[1];
      Lt[r * 65 + c + 2] = v[2]; Lt[r * 65 + c + 3] = v[3];
    }
    __syncthreads();
    const int n = tid >> 2, kg = (tid & 3) * 16;
    bf16x8 o0, o1;
#pragma unroll
    for (int e = 0; e < 8; ++e) {
      o0[e] = (bf16)Lt[(kg + e) * 65 + n];
      o1[e] = (bf16)Lt[(kg + 8 + e) * 65 + n];
    }
    *(bf16x8*)&WT[(long)(tn0 + n) * K + tk0 + kg] = o0;
    *(bf16x8*)&WT[(long)(tn0 + n) * K + tk0 + kg + 8] = o1;
  }
}

// ---------------- unified projections: K (384 blocks, Kd=64) + QV (768 blocks) ----------------
__global__ __launch_bounds__(256) void proj_all(
    const bf16* __restrict__ Xb_bf, const bf16* __restrict__ WkT,
    const bf16* __restrict__ Xd_bf, const bf16* __restrict__ WqvT,
    const float* __restrict__ bk, const float* __restrict__ bq,
    const float* __restrict__ bv,
    bf16* __restrict__ Kb, bf16* __restrict__ Qb, bf16* __restrict__ VTb) {
  __shared__ __attribute__((aligned(16))) bf16 aL[2 * 128 * 32];
  __shared__ __attribute__((aligned(16))) bf16 bL[2 * 128 * 32];
  const int tid = threadIdx.x;
  const int lane = tid & 63;
  const int wid = tid >> 6;
  const int wr = wid >> 1, wc = wid & 1;
  const int id = blockIdx.x;
  const bool isK = id < 384;
  int by, bx, lda, Kd, N;
  const bf16 *A, *BT;
  if (isK) {
    by = id & 63; bx = id >> 6;
    A = Xb_bf; BT = WkT; lda = DB; Kd = DB; N = DM;
  } else {
    int t = id - 384;
    by = t & 63; bx = t >> 6;
    A = Xd_bf; BT = WqvT; lda = DM; Kd = DM; N = 2 * DM;
  }
  const int m0 = by * 128, n0 = bx * 128;

  f32x4 acc[4][4] = {};

  for (int k0 = 0; k0 < Kd; k0 += 64) {
#pragma unroll
    for (int h = 0; h < 2; ++h) {
#pragma unroll
      for (int p = 0; p < 2; ++p) {
        int f = (p * 256 + tid) * 8;
        int row = f >> 5, col = f & 31;
        gld_lds16(A + (long)(m0 + row) * lda + k0 + h * 32 + col, &aL[h * 4096 + f]);
      }
#pragma unroll
      for (int p = 0; p < 2; ++p) {
        int f = (p * 256 + tid) * 8;
        int row = f >> 5, col = f & 31;
        int nn = n0 + row;
        nn = nn < N ? nn : N - 1;
        gld_lds16(BT + (long)nn * lda + k0 + h * 32 + col, &bL[h * 4096 + f]);
      }
    }
    __syncthreads();

    const int rsel = lane & 15, ksel = (lane >> 4) * 8;
#pragma unroll
    for (int h = 0; h < 2; ++h) {
      bf16x8 af[4], bfr[4];
#pragma unroll
      for (int m = 0; m < 4; ++m)
        af[m] = *(const bf16x8*)&aL[h * 4096 + (wr * 64 + m * 16 + rsel) * 32 + ksel];
#pragma unroll
      for (int n = 0; n < 4; ++n)
        bfr[n] = *(const bf16x8*)&bL[h * 4096 + (wc * 64 + n * 16 + rsel) * 32 + ksel];
#pragma unroll
      for (int m = 0; m < 4; ++m)
#pragma unroll
        for (int n = 0; n < 4; ++n)
          acc[m][n] = __builtin_amdgcn_mfma_f32_16x16x32_bf16(af[m], bfr[n], acc[m][n], 0, 0, 0);
    }
    __syncthreads();
  }

  const int rl = (lane >> 4) * 4, cl = lane & 15;

  if (!isK && n0 >= DM) {
    const int d0 = n0 - DM;
    float bvv[4];
#pragma unroll
    for (int n = 0; n < 4; ++n)
      bvv[n] = bv[d0 + wc * 64 + n * 16 + cl];
#pragma unroll
    for (int m = 0; m < 4; ++m)
#pragma unroll
      for (int n = 0; n < 4; ++n)
#pragma unroll
        for (int j = 0; j < 4; ++j) {
          int row = wr * 64 + m * 16 + rl + j;
          int col = wc * 64 + n * 16 + cl;
          int sw = row ^ ((col & 7) << 4);
          bf16 val = (bf16)(acc[m][n][j] + bvv[n]);
          if (col < 64) aL[col * 128 + sw] = val;
          else          bL[(col - 64) * 128 + sw] = val;
        }
    __syncthreads();
    const int b = m0 >> 10, s0 = m0 & 1023;
#pragma unroll
    for (int it = 0; it < 8; ++it) {
      int d = it * 16 + (tid >> 4);
      int s = (tid & 15) * 8;
      int sw = s ^ ((d & 7) << 4);
      bf16x8 v = (d < 64) ? *(const bf16x8*)&aL[d * 128 + sw]
                          : *(const bf16x8*)&bL[(d - 64) * 128 + sw];
      *(bf16x8*)&VTb[((long)(b * DM + d0 + d) << 10) + s0 + s] = v;
    }
    return;
  }

  const float* cb = isK ? bk : bq;
  bf16* out = isK ? Kb : Qb;
  float bvv[4];
#pragma unroll
  for (int n = 0; n < 4; ++n)
    bvv[n] = cb[n0 + wc * 64 + n * 16 + cl];
#pragma unroll
  for (int m = 0; m < 4; ++m)
#pragma unroll
    for (int n = 0; n < 4; ++n)
#pragma unroll
      for (int j = 0; j < 4; ++j) {
        int row = wr * 64 + m * 16 + rl + j;
        int col = wc * 64 + n * 16 + cl;
        bf16 val = (bf16)(acc[m][n][j] + bvv[n]);
        if (row < 64) aL[row * 128 + col] = val;
        else          bL[(row - 64) * 128 + col] = val;
      }
  __syncthreads();
#pragma unroll
  for (int it = 0; it < 8; ++it) {
    int row = it * 16 + (tid >> 4);
    int col = (tid & 15) * 8;
    bf16x8 v = (row < 64) ? *(const bf16x8*)&aL[row * 128 + col]
                          : *(const bf16x8*)&bL[(row - 64) * 128 + col];
    *(bf16x8*)&out[(long)(m0 + row) * DM + n0 + col] = v;
  }
}

// fallback: E was written f32 into attn; normalize in place.
__global__ __launch_bounds__(256) void rowsum_scale_f32(float* __restrict__ attn) {
  const int row = blockIdx.x * 4 + (threadIdx.x >> 6);
  const int lane = threadIdx.x & 63;
  float* ar = attn + ((long)row << 10);
  f32x4 v[4];
#pragma unroll
  for (int i = 0; i < 4; ++i) v[i] = *(const f32x4*)&ar[i * 256 + lane * 4];
  float s = 0.0f;
#pragma unroll
  for (int i = 0; i < 4; ++i)
#pragma unroll
    for (int j = 0; j < 4; ++j) s += v[i][j];
  for (int d = 1; d < 64; d <<= 1) s += __shfl_xor(s, d);
  float iv = 1.0f / s;
#pragma unroll
  for (int i = 0; i < 4; ++i) {
#pragma unroll
    for (int j = 0; j < 4; ++j) v[i][j] *= iv;
    *(f32x4*)&ar[i * 256 + lane * 4] = v[i];
  }
}

// ---------------- dedicated PV: 512 blocks of 64 rows x 192 cols ----------------
__global__ __launch_bounds__(256) void pv_attn(
    const bf16* __restrict__ E, const bf16* __restrict__ VT,
    const float* __restrict__ part, bf16* __restrict__ ctx,
    float* __restrict__ attn) {
  __shared__ __attribute__((aligned(16))) bf16 aL[2 * 64 * 32];   // 8 KB
  __shared__ __attribute__((aligned(16))) bf16 bL[2 * 192 * 32];  // 24 KB
  __shared__ float ivL[64];
  const int tid = threadIdx.x;
  const int lane = tid & 63;
  const int wid = tid >> 6;
  const int wr = wid >> 1, wc = wid & 1;
  const int id = blockIdx.x;
  const int bz = id & 31;
  const int by = id >> 5;
  const int m0 = by * 64;
  const int b = bz >> 2, h = bz & 3;

  const bf16* Ab = E + ((long)bz << 20);
  const bf16* Bb = VT + (((long)(b * DM + h * HD)) << 10);

  if (tid < 64) {
    const float* p = part + ((((long)bz << 10) + m0 + tid) << 4);
    float s = 0.0f;
#pragma unroll
    for (int i = 0; i < 16; ++i) s += p[i];
    ivL[tid] = 1.0f / s;
  }
  __syncthreads();
  const float iv0 = ivL[tid >> 2];

  f32x4 acc[2][6] = {};
  const int rsel = lane & 15, ksel = (lane >> 4) * 8;

  for (int k0 = 0; k0 < SEQ; k0 += 64) {
#pragma unroll
    for (int h2 = 0; h2 < 2; ++h2) {
      {
        int f = tid * 8;
        int row = f >> 5, col = f & 31;
        gld_lds16(Ab + (long)(m0 + row) * SEQ + k0 + h2 * 32 + col, &aL[h2 * 2048 + f]);
      }
#pragma unroll
      for (int p = 0; p < 3; ++p) {
        int f = (p * 256 + tid) * 8;
        int row = f >> 5, col = f & 31;
        gld_lds16(Bb + (long)row * SEQ + k0 + h2 * 32 + col, &bL[h2 * 6144 + f]);
      }
    }
    __syncthreads();

    // MFMA first: keep matrix pipe fed; nt-stores drain behind it
#pragma unroll
    for (int h2 = 0; h2 < 2; ++h2) {
      bf16x8 af[2], bfr[6];
#pragma unroll
      for (int m = 0; m < 2; ++m)
        af[m] = *(const bf16x8*)&aL[h2 * 2048 + (wr * 32 + m * 16 + rsel) * 32 + ksel];
#pragma unroll
      for (int n = 0; n < 6; ++n)
        bfr[n] = *(const bf16x8*)&bL[h2 * 6144 + (wc * 96 + n * 16 + rsel) * 32 + ksel];
#pragma unroll
      for (int m = 0; m < 2; ++m)
#pragma unroll
        for (int n = 0; n < 6; ++n)
          acc[m][n] = __builtin_amdgcn_mfma_f32_16x16x32_bf16(af[m], bfr[n], acc[m][n], 0, 0, 0);
    }

    // attn f32 write from staged E (*inv), nontemporal
#pragma unroll
    for (int h2 = 0; h2 < 2; ++h2) {
      int f = tid * 8;
      int row = f >> 5, col = f & 31;
      bf16x8 e = *(const bf16x8*)&aL[h2 * 2048 + f];
      f32x4 w0, w1;
      w0[0] = (float)e[0] * iv0; w0[1] = (float)e[1] * iv0;
      w0[2] = (float)e[2] * iv0; w0[3] = (float)e[3] * iv0;
      w1[0] = (float)e[4] * iv0; w1[1] = (float)e[5] * iv0;
      w1[2] = (float)e[6] * iv0; w1[3] = (float)e[7] * iv0;
      float* ap = attn + ((long)bz << 20) + ((long)(m0 + row) << 10) + k0 + h2 * 32 + col;
      __builtin_nontemporal_store(w0, (f32x4*)ap);
      __builtin_nontemporal_store(w1, (f32x4*)(ap + 4));
    }
    __syncthreads();
  }

  const int rl = (lane >> 4) * 4, cl = lane & 15;
#pragma unroll
  for (int m = 0; m < 2; ++m)
#pragma unroll
    for (int n = 0; n < 6; ++n)
#pragma unroll
      for (int j = 0; j < 4; ++j) {
        int row = wr * 32 + m * 16 + rl + j;
        int col = wc * 96 + n * 16 + cl;
        bL[row * 192 + col] = (bf16)(acc[m][n][j] * ivL[row]);
      }
  __syncthreads();
#pragma unroll
  for (int it = 0; it < 6; ++it) {
    int idx2 = it * 256 + tid;
    int row = idx2 / 24;
    int col = (idx2 % 24) * 8;
    bf16x8 v = *(const bf16x8*)&bL[row * 192 + col];
    *(bf16x8*)&ctx[(long)(b * SEQ + m0 + row) * DM + h * HD + col] = v;
  }
}

// ---------------- GEMM (A row-major [M,K] bf16, BT row-major [N,K] bf16) ----------------
// NH sub-buffers of [128][32] staged before ONE barrier pair (BK = NH*32).
// MODE 2: E = exp bf16 staged + row-partials (scores)   [NH=3, Kd=192 -> 2 pairs]
// MODE 7: fallback f32 E into attn                      [NH=3]
// MODE 5: PV fallback (A f32)                           [NH=2, Kd=1024]
// MODE 4: final x f32, staged epilogue                  [NH=3, Kd=768 -> 8 pairs]
template <int MODE>
__global__ __launch_bounds__(256) void gemm_bt(
    const bf16* __restrict__ A, int lda,
    const bf16* __restrict__ BT, int ldb,
    const float* __restrict__ Af,
    int M, int N, int Kd,
    const float* __restrict__ cb1,
    const float* __restrict__ cb2,
    const float* __restrict__ resid,
    void* __restrict__ out, void* __restrict__ out2) {
  constexpr int NH = (MODE == 5) ? 2 : 3;
  __shared__ __attribute__((aligned(16))) bf16 aL[3 * 128 * 32];
  __shared__ __attribute__((aligned(16))) bf16 bL[3 * 128 * 32];
  const int tid = threadIdx.x;
  const int lane = tid & 63;
  const int wid = tid >> 6;
  const int wr = wid >> 1, wc = wid & 1;
  int bx, by, bz;
  if constexpr (MODE == 2 || MODE == 7) {
    int idd = blockIdx.x;
    bz = idd & 31;
    int t = idd >> 5;
    bx = t & 7;
    by = t >> 3;
  } else if constexpr (MODE == 5) {
    int idd = blockIdx.x;
    bz = idd & 31;
    bx = (idd >> 5) & 1;
    by = idd >> 6;
  } else {
    int idd = blockIdx.x;
    by = idd & 63;
    bx = idd >> 6;
    bz = 0;
  }
  const int m0 = by * 128, n0 = bx * 128;

  const bf16* Ab = A;
  const bf16* Bb = BT;
  const float* Afb = Af;
  if constexpr (MODE == 2 || MODE == 7) {
    long o = ((long)((bz >> 2) * SEQ)) * DM + (long)(bz & 3) * HD;
    Ab = A + o;
    Bb = BT + o;
  }
  if constexpr (MODE == 5) {
    Bb = BT + (((long)((bz >> 2) * DM + (bz & 3) * HD)) << 10);
    Afb = Af + ((long)bz << 20);
  }

  f32x4 acc[4][4] = {};

  for (int k0 = 0; k0 < Kd; k0 += NH * 32) {
#pragma unroll
    for (int h = 0; h < NH; ++h) {
      if constexpr (MODE == 5) {
#pragma unroll
        for (int p = 0; p < 2; ++p) {
          int f = (p * 256 + tid) * 8;
          int row = f >> 5, col = f & 31;
          const float* g = Afb + (long)(m0 + row) * lda + k0 + h * 32 + col;
          f32x4 x0 = *(const f32x4*)g;
          f32x4 x1 = *(const f32x4*)(g + 4);
          bf16x8 t;
          t[0] = (bf16)x0[0]; t[1] = (bf16)x0[1]; t[2] = (bf16)x0[2]; t[3] = (bf16)x0[3];
          t[4] = (bf16)x1[0]; t[5] = (bf16)x1[1]; t[6] = (bf16)x1[2]; t[7] = (bf16)x1[3];
          *(bf16x8*)&aL[h * 4096 + f] = t;
        }
      } else {
#pragma unroll
        for (int p = 0; p < 2; ++p) {
          int f = (p * 256 + tid) * 8;
          int row = f >> 5, col = f & 31;
          gld_lds16(Ab + (long)(m0 + row) * lda + k0 + h * 32 + col, &aL[h * 4096 + f]);
        }
      }
#pragma unroll
      for (int p = 0; p < 2; ++p) {
        int f = (p * 256 + tid) * 8;
        int row = f >> 5, col = f & 31;
        int nn = n0 + row;
        nn = nn < N ? nn : N - 1;
        gld_lds16(Bb + (long)nn * ldb + k0 + h * 32 + col, &bL[h * 4096 + f]);
      }
    }
    __syncthreads();

    const int rsel = lane & 15, ksel = (lane >> 4) * 8;
#pragma unroll
    for (int h = 0; h < NH; ++h) {
      bf16x8 af[4], bfr[4];
#pragma unroll
      for (int m = 0; m < 4; ++m)
        af[m] = *(const bf16x8*)&aL[h * 4096 + (wr * 64 + m * 16 + rsel) * 32 + ksel];
#pragma unroll
      for (int n = 0; n < 4; ++n)
        bfr[n] = *(const bf16x8*)&bL[h * 4096 + (wc * 64 + n * 16 + rsel) * 32 + ksel];
#pragma unroll
      for (int m = 0; m < 4; ++m)
#pragma unroll
        for (int n = 0; n < 4; ++n)
          acc[m][n] = __builtin_amdgcn_mfma_f32_16x16x32_bf16(af[m], bfr[n], acc[m][n], 0, 0, 0);
    }
    __syncthreads();
  }

  const int rl = (lane >> 4) * 4, cl = lane & 15;

  if constexpr (MODE == 2) {
    float bvv[4];
#pragma unroll
    for (int n = 0; n < 4; ++n)
      bvv[n] = cb2[(bz << 10) + n0 + wc * 64 + n * 16 + cl];
#pragma unroll
    for (int m = 0; m < 4; ++m)
#pragma unroll
      for (int n = 0; n < 4; ++n)
#pragma unroll
        for (int j = 0; j < 4; ++j)
          acc[m][n][j] = __expf(fmaf(acc[m][n][j], SCALE, bvv[n]));
    float* part = (float*)out2;
#pragma unroll
    for (int m = 0; m < 4; ++m) {
#pragma unroll
      for (int j = 0; j < 4; ++j) {
        float s = acc[m][0][j] + acc[m][1][j] + acc[m][2][j] + acc[m][3][j];
#pragma unroll
        for (int d = 1; d < 16; d <<= 1) s += __shfl_xor(s, d);
        if (cl == 0) {
          int mg = m0 + wr * 64 + m * 16 + rl + j;
          part[((((long)bz << 10) + mg) << 4) + bx * 2 + wc] = s;
        }
      }
    }
#pragma unroll
    for (int m = 0; m < 4; ++m)
#pragma unroll
      for (int n = 0; n < 4; ++n)
#pragma unroll
        for (int j = 0; j < 4; ++j) {
          int row = wr * 64 + m * 16 + rl + j;
          int col = wc * 64 + n * 16 + cl;
          bf16* Lt = (row < 64) ? &aL[row * 128 + col] : &bL[(row - 64) * 128 + col];
          *Lt = (bf16)acc[m][n][j];
        }
    __syncthreads();
#pragma unroll
    for (int it = 0; it < 8; ++it) {
      int row = it * 16 + (tid >> 4);
      int col = (tid & 15) * 8;
      bf16x8 v = (row < 64) ? *(const bf16x8*)&aL[row * 128 + col]
                            : *(const bf16x8*)&bL[(row - 64) * 128 + col];
      *(bf16x8*)&((bf16*)out)[((long)bz << 20) + ((long)(m0 + row) << 10) + n0 + col] = v;
    }
    return;
  }

  if constexpr (MODE == 4) {
    // staged f32 epilogue: two 64-row halves; +cb1+resid folded into coalesced write
#pragma unroll
    for (int half = 0; half < 2; ++half) {
      if (wr == half) {
#pragma unroll
        for (int m = 0; m < 4; ++m)
#pragma unroll
          for (int n = 0; n < 4; ++n)
#pragma unroll
            for (int j = 0; j < 4; ++j) {
              int r = m * 16 + rl + j;
              int col = wc * 64 + n * 16 + cl;
              float* Lf = (r < 32) ? (float*)aL + r * 128
                                   : (float*)bL + (r - 32) * 128;
              Lf[col] = acc[m][n][j];
            }
      }
      __syncthreads();
#pragma unroll
      for (int it = 0; it < 8; ++it) {
        int r = it * 8 + (tid >> 5);
        int c = (tid & 31) * 4;
        const float* Lf = (r < 32) ? (const float*)aL + r * 128
                                   : (const float*)bL + (r - 32) * 128;
        f32x4 v = *(const f32x4*)&Lf[c];
        long o = (long)(m0 + half * 64 + r) * DM + n0 + c;
        f32x4 rs = *(const f32x4*)&resid[o];
        f32x4 y;
        y[0] = v[0] + cb1[n0 + c] + rs[0];
        y[1] = v[1] + cb1[n0 + c + 1] + rs[1];
        y[2] = v[2] + cb1[n0 + c + 2] + rs[2];
        y[3] = v[3] + cb1[n0 + c + 3] + rs[3];
        *(f32x4*)&((float*)out)[o] = y;
      }
      __syncthreads();
    }
    return;
  }

#pragma unroll
  for (int m = 0; m < 4; ++m) {
#pragma unroll
    for (int n = 0; n < 4; ++n) {
      int ng = n0 + wc * 64 + n * 16 + cl;
      if (ng >= N) continue;
#pragma unroll
      for (int j = 0; j < 4; ++j) {
        int mg = m0 + wr * 64 + m * 16 + rl + j;
        float v = acc[m][n][j];
        if constexpr (MODE == 7) {
          ((float*)out)[((long)bz << 20) + ((long)mg << 10) + ng] =
              __expf(fmaf(v, SCALE, cb2[(bz << 10) + ng]));
        } else if constexpr (MODE == 5) {
          ((bf16*)out)[(long)((bz >> 2) * SEQ + mg) * DM + (bz & 3) * HD + ng] = (bf16)v;
        }
      }
    }
  }
}

// ---------------- layernorm (one wave per row of 768, in place) ----------------
__global__ __launch_bounds__(256) void layernorm_rows(float* x, const float* __restrict__ gam,
                                                      const float* __restrict__ bet) {
  int row = blockIdx.x * 4 + (threadIdx.x >> 6);
  int lane = threadIdx.x & 63;
  float* r = x + (long)row * DM;
  f32x4 v[3];
#pragma unroll
  for (int i = 0; i < 3; ++i) v[i] = *(const f32x4*)&r[i * 256 + lane * 4];
  float s = 0.0f, ss = 0.0f;
#pragma unroll
  for (int i = 0; i < 3; ++i)
#pragma unroll
    for (int j = 0; j < 4; ++j) {
      s += v[i][j];
      ss += v[i][j] * v[i][j];
    }
  for (int d = 1; d < 64; d <<= 1) {
    s += __shfl_xor(s, d);
    ss += __shfl_xor(ss, d);
  }
  float mu = s * (1.0f / 768.0f);
  float var = ss * (1.0f / 768.0f) - mu * mu;
  float rs = 1.0f / sqrtf(var + 1e-5f);
#pragma unroll
  for (int i = 0; i < 3; ++i) {
#pragma unroll
    for (int j = 0; j < 4; ++j) {
      int c = i * 256 + lane * 4 + j;
      v[i][j] = (v[i][j] - mu) * rs * gam[c] + bet[c];
    }
    *(f32x4*)&r[i * 256 + lane * 4] = v[i];
  }
}

// ---------------- launcher ----------------
extern "C" void kernel_launch(void* const* d_in, const int* in_sizes, int n_in,
                              void* d_out, int out_size, void* d_ws, size_t ws_size,
                              hipStream_t stream) {
  const float* Xd = (const float*)d_in[0];
  const float* Xb = (const float*)d_in[1];
  const float* Wq = (const float*)d_in[2];
  const float* bq = (const float*)d_in[3];
  const float* Wk = (const float*)d_in[4];
  const float* bk = (const float*)d_in[5];
  const float* Wv = (const float*)d_in[6];
  const float* bv = (const float*)d_in[7];
  const float* Wb1 = (const float*)d_in[8];
  const float* bb1 = (const float*)d_in[9];
  const float* Wb2 = (const float*)d_in[10];
  const float* bb2 = (const float*)d_in[11];
  const float* Wo = (const float*)d_in[12];
  const float* bo = (const float*)d_in[13];
  const float* lng = (const float*)d_in[14];
  const float* lnb = (const float*)d_in[15];

  float* y = (float*)d_out;                  // 8192*768 f32
  float* attn = y + (long)MROWS * DM;        // 32*1024*1024 f32

  char* w = (char*)d_ws;
  bf16* Xd_bf = (bf16*)w; w += (long)MROWS * DM * 2;   // later reused as ctx
  bf16* Xb_bf = (bf16*)w; w += (long)MROWS * DB * 2;
  bf16* WqvT = (bf16*)w; w += (long)2 * DM * DM * 2;   // [1536][768]
  bf16* WkT = (bf16*)w; w += (long)DM * DB * 2;
  bf16* WoT = (bf16*)w; w += (long)DM * DM * 2;
  bf16* Qb = (bf16*)w; w += (long)MROWS * DM * 2;
  bf16* Kb = (bf16*)w; w += (long)MROWS * DM * 2;
  bf16* VTb = (bf16*)w; w += (long)MROWS * DM * 2;
  float* biasarr = (float*)w; w += (long)BATCH * NHEADS * SEQ * 4;
  float* part = (float*)w; w += (long)32 * SEQ * 16 * 4;   // 2 MB partials
  bf16* Sb = (bf16*)w; w += (long)32 * SEQ * SEQ * 2;      // 64 MB E buffer
  const bool useS = ((size_t)(w - (char*)d_ws)) <= ws_size;
  bf16* ctxb = Xd_bf;  // Xd_bf dead after QV projection; reuse for ctx

  dim3 blk(256);
  // fused prologue: cvt Xd, cvt Xb, bias MLP, tiled weight transposes
  prologue<<<7132, blk, 0, stream>>>(Xd, Xd_bf, Xb, Xb_bf, Wq, Wv, Wk, Wo,
                                     WqvT, WqvT + (long)DM * DM, WkT, WoT,
                                     Wb1, bb1, Wb2, bb2, biasarr);

  // K + [Q|V] projections in one dispatch
  proj_all<<<1152, blk, 0, stream>>>(Xb_bf, WkT, Xd_bf, WqvT, bk, bq, bv, Kb, Qb, VTb);

  if (useS) {
    // E = exp(QK^T*scale + bias) bf16 (BK=96, staged coalesced) + row-partials
    gemm_bt<2><<<2048, blk, 0, stream>>>(Qb, DM, Kb, DM, nullptr, SEQ, SEQ, HD,
                                         nullptr, biasarr, nullptr, Sb, part);
    // PV: 64x192 blocks, E staged once, attn written in k-loop, ctx staged
    pv_attn<<<512, blk, 0, stream>>>(Sb, VTb, part, ctxb, attn);
  } else {
    gemm_bt<7><<<2048, blk, 0, stream>>>(Qb, DM, Kb, DM, nullptr, SEQ, SEQ, HD,
                                         nullptr, biasarr, nullptr, attn, nullptr);
    rowsum_scale_f32<<<8192, blk, 0, stream>>>(attn);
    gemm_bt<5><<<512, blk, 0, stream>>>(nullptr, SEQ, VTb, SEQ, attn, SEQ, HD, SEQ,
                                        nullptr, nullptr, nullptr, ctxb, nullptr);
  }
  // x = ctx @ Wo + bo + resid -> y region (BK=96, staged f32 epilogue), then LN
  gemm_bt<4><<<384, blk, 0, stream>>>(ctxb, DM, WoT, DM, nullptr, MROWS, DM, DM,
                                      bo, nullptr, Xd, y, nullptr);
  layernorm_rows<<<2048, 256, 0, stream>>>(y, lng, lnb);
}

// Round 21
// 169.026 us; speedup vs baseline: 1.0803x; 1.0803x over previous
//
#include <hip/hip_runtime.h>
#include <hip/hip_bf16.h>
#include <math.h>
#include <stdint.h>

typedef __bf16 bf16;
typedef __bf16 bf16x8 __attribute__((ext_vector_type(8)));
typedef __bf16 bf16x4v __attribute__((ext_vector_type(4)));
typedef float f32x4 __attribute__((ext_vector_type(4)));

#define NHEADS 4
#define DM 768
#define DB 64
#define HD 192
#define BATCH 8
#define SEQ 1024
#define MROWS 8192
#define SCALE 0.07216878364870323f

__device__ __forceinline__ void gld_lds16(const void* g, void* l) {
  __builtin_amdgcn_global_load_lds(
      (__attribute__((address_space(1))) void*)(void*)g,
      (__attribute__((address_space(3))) void*)l, 16, 0, 0);
}

// ---------------- fused prologue: cvt Xd, cvt Xb, bias MLP, tiled weight transposes ----------------
__global__ __launch_bounds__(256) void prologue(
    const float* __restrict__ Xd, bf16* __restrict__ Xd_bf,
    const float* __restrict__ Xb, bf16* __restrict__ Xb_bf,
    const float* __restrict__ Wq, const float* __restrict__ Wv,
    const float* __restrict__ Wk, const float* __restrict__ Wo,
    bf16* __restrict__ WT0, bf16* __restrict__ WT1,
    bf16* __restrict__ WT2, bf16* __restrict__ WT3,
    const float* __restrict__ Wb1, const float* __restrict__ bb1,
    const float* __restrict__ Wb2, const float* __restrict__ bb2,
    float* __restrict__ biasarr) {
  __shared__ float Lt[64 * 65];
  const int id = blockIdx.x;
  const int tid = threadIdx.x;
  if (id < 6656) {
    const float* in = (id < 6144) ? Xd : Xb;
    bf16* out = (id < 6144) ? Xd_bf : Xb_bf;
    long i = (long)(id < 6144 ? id : id - 6144) * 256 + tid;
    f32x4 v = *(const f32x4*)&in[i * 4];
    bf16x4v t;
    t[0] = (bf16)v[0]; t[1] = (bf16)v[1]; t[2] = (bf16)v[2]; t[3] = (bf16)v[3];
    *(bf16x4v*)&out[i * 4] = t;
  } else if (id < 6688) {
    int idx = (id - 6656) * 256 + tid;
    const float* x = Xb + (long)idx * DB;
    float h[8];
#pragma unroll
    for (int j = 0; j < 8; ++j) h[j] = bb1[j];
    for (int k = 0; k < DB; ++k) {
      float xv = x[k];
#pragma unroll
      for (int j = 0; j < 8; ++j) h[j] = fmaf(xv, Wb1[k * 8 + j], h[j]);
    }
#pragma unroll
    for (int j = 0; j < 8; ++j) {
      float a = h[j];
      h[j] = 0.5f * a * (1.0f + erff(a * 0.7071067811865476f));
    }
    int b = idx >> 10, s = idx & 1023;
#pragma unroll
    for (int o = 0; o < 4; ++o) {
      float a = bb2[o];
#pragma unroll
      for (int j = 0; j < 8; ++j) a = fmaf(h[j], Wb2[j * 4 + o], a);
      biasarr[((long)(b * 4 + o) << 10) + s] = a;
    }
  } else {
    // 64x64 tiled transpose: coalesced f32x4 reads, LDS pad-65, bf16x8 writes
    int wi = id - 6688;
    const float* W;
    bf16* WT;
    int K, tIdx;
    if (wi < 144)      { W = Wq; WT = WT0; K = DM; tIdx = wi; }
    else if (wi < 288) { W = Wv; WT = WT1; K = DM; tIdx = wi - 144; }
    else if (wi < 300) { W = Wk; WT = WT2; K = DB; tIdx = wi - 288; }
    else               { W = Wo; WT = WT3; K = DM; tIdx = wi - 300; }
    const int tk0 = (tIdx / 12) * 64;
    const int tn0 = (tIdx % 12) * 64;
#pragma unroll
    for (int p = 0; p < 4; ++p) {
      int r = p * 16 + (tid >> 4);
      int c = (tid & 15) * 4;
      f32x4 v = *(const f32x4*)&W[(long)(tk0 + r) * DM + tn0 + c];
      Lt[r * 65 + c] = v[0]; Lt[r * 65 + c + 1] = v[1];
      Lt[r * 65 + c + 2] = v[2]; Lt[r * 65 + c + 3] = v[3];
    }
    __syncthreads();
    const int n = tid >> 2, kg = (tid & 3) * 16;
    bf16x8 o0, o1;
#pragma unroll
    for (int e = 0; e < 8; ++e) {
      o0[e] = (bf16)Lt[(kg + e) * 65 + n];
      o1[e] = (bf16)Lt[(kg + 8 + e) * 65 + n];
    }
    *(bf16x8*)&WT[(long)(tn0 + n) * K + tk0 + kg] = o0;
    *(bf16x8*)&WT[(long)(tn0 + n) * K + tk0 + kg + 8] = o1;
  }
}

// ---------------- unified projections: K (384 blocks, Kd=64) + QV (768 blocks) ----------------
__global__ __launch_bounds__(256) void proj_all(
    const bf16* __restrict__ Xb_bf, const bf16* __restrict__ WkT,
    const bf16* __restrict__ Xd_bf, const bf16* __restrict__ WqvT,
    const float* __restrict__ bk, const float* __restrict__ bq,
    const float* __restrict__ bv,
    bf16* __restrict__ Kb, bf16* __restrict__ Qb, bf16* __restrict__ VTb) {
  __shared__ __attribute__((aligned(16))) bf16 aL[2 * 128 * 32];
  __shared__ __attribute__((aligned(16))) bf16 bL[2 * 128 * 32];
  const int tid = threadIdx.x;
  const int lane = tid & 63;
  const int wid = tid >> 6;
  const int wr = wid >> 1, wc = wid & 1;
  const int id = blockIdx.x;
  const bool isK = id < 384;
  int by, bx, lda, Kd, N;
  const bf16 *A, *BT;
  if (isK) {
    by = id & 63; bx = id >> 6;
    A = Xb_bf; BT = WkT; lda = DB; Kd = DB; N = DM;
  } else {
    int t = id - 384;
    by = t & 63; bx = t >> 6;
    A = Xd_bf; BT = WqvT; lda = DM; Kd = DM; N = 2 * DM;
  }
  const int m0 = by * 128, n0 = bx * 128;

  f32x4 acc[4][4] = {};

  for (int k0 = 0; k0 < Kd; k0 += 64) {
#pragma unroll
    for (int h = 0; h < 2; ++h) {
#pragma unroll
      for (int p = 0; p < 2; ++p) {
        int f = (p * 256 + tid) * 8;
        int row = f >> 5, col = f & 31;
        gld_lds16(A + (long)(m0 + row) * lda + k0 + h * 32 + col, &aL[h * 4096 + f]);
      }
#pragma unroll
      for (int p = 0; p < 2; ++p) {
        int f = (p * 256 + tid) * 8;
        int row = f >> 5, col = f & 31;
        int nn = n0 + row;
        nn = nn < N ? nn : N - 1;
        gld_lds16(BT + (long)nn * lda + k0 + h * 32 + col, &bL[h * 4096 + f]);
      }
    }
    __syncthreads();

    const int rsel = lane & 15, ksel = (lane >> 4) * 8;
#pragma unroll
    for (int h = 0; h < 2; ++h) {
      bf16x8 af[4], bfr[4];
#pragma unroll
      for (int m = 0; m < 4; ++m)
        af[m] = *(const bf16x8*)&aL[h * 4096 + (wr * 64 + m * 16 + rsel) * 32 + ksel];
#pragma unroll
      for (int n = 0; n < 4; ++n)
        bfr[n] = *(const bf16x8*)&bL[h * 4096 + (wc * 64 + n * 16 + rsel) * 32 + ksel];
#pragma unroll
      for (int m = 0; m < 4; ++m)
#pragma unroll
        for (int n = 0; n < 4; ++n)
          acc[m][n] = __builtin_amdgcn_mfma_f32_16x16x32_bf16(af[m], bfr[n], acc[m][n], 0, 0, 0);
    }
    __syncthreads();
  }

  const int rl = (lane >> 4) * 4, cl = lane & 15;

  if (!isK && n0 >= DM) {
    const int d0 = n0 - DM;
    float bvv[4];
#pragma unroll
    for (int n = 0; n < 4; ++n)
      bvv[n] = bv[d0 + wc * 64 + n * 16 + cl];
#pragma unroll
    for (int m = 0; m < 4; ++m)
#pragma unroll
      for (int n = 0; n < 4; ++n)
#pragma unroll
        for (int j = 0; j < 4; ++j) {
          int row = wr * 64 + m * 16 + rl + j;
          int col = wc * 64 + n * 16 + cl;
          int sw = row ^ ((col & 7) << 4);
          bf16 val = (bf16)(acc[m][n][j] + bvv[n]);
          if (col < 64) aL[col * 128 + sw] = val;
          else          bL[(col - 64) * 128 + sw] = val;
        }
    __syncthreads();
    const int b = m0 >> 10, s0 = m0 & 1023;
#pragma unroll
    for (int it = 0; it < 8; ++it) {
      int d = it * 16 + (tid >> 4);
      int s = (tid & 15) * 8;
      int sw = s ^ ((d & 7) << 4);
      bf16x8 v = (d < 64) ? *(const bf16x8*)&aL[d * 128 + sw]
                          : *(const bf16x8*)&bL[(d - 64) * 128 + sw];
      *(bf16x8*)&VTb[((long)(b * DM + d0 + d) << 10) + s0 + s] = v;
    }
    return;
  }

  const float* cb = isK ? bk : bq;
  bf16* out = isK ? Kb : Qb;
  float bvv[4];
#pragma unroll
  for (int n = 0; n < 4; ++n)
    bvv[n] = cb[n0 + wc * 64 + n * 16 + cl];
#pragma unroll
  for (int m = 0; m < 4; ++m)
#pragma unroll
    for (int n = 0; n < 4; ++n)
#pragma unroll
      for (int j = 0; j < 4; ++j) {
        int row = wr * 64 + m * 16 + rl + j;
        int col = wc * 64 + n * 16 + cl;
        bf16 val = (bf16)(acc[m][n][j] + bvv[n]);
        if (row < 64) aL[row * 128 + col] = val;
        else          bL[(row - 64) * 128 + col] = val;
      }
  __syncthreads();
#pragma unroll
  for (int it = 0; it < 8; ++it) {
    int row = it * 16 + (tid >> 4);
    int col = (tid & 15) * 8;
    bf16x8 v = (row < 64) ? *(const bf16x8*)&aL[row * 128 + col]
                          : *(const bf16x8*)&bL[(row - 64) * 128 + col];
    *(bf16x8*)&out[(long)(m0 + row) * DM + n0 + col] = v;
  }
}

// fallback: E was written f32 into attn; normalize in place.
__global__ __launch_bounds__(256) void rowsum_scale_f32(float* __restrict__ attn) {
  const int row = blockIdx.x * 4 + (threadIdx.x >> 6);
  const int lane = threadIdx.x & 63;
  float* ar = attn + ((long)row << 10);
  f32x4 v[4];
#pragma unroll
  for (int i = 0; i < 4; ++i) v[i] = *(const f32x4*)&ar[i * 256 + lane * 4];
  float s = 0.0f;
#pragma unroll
  for (int i = 0; i < 4; ++i)
#pragma unroll
    for (int j = 0; j < 4; ++j) s += v[i][j];
  for (int d = 1; d < 64; d <<= 1) s += __shfl_xor(s, d);
  float iv = 1.0f / s;
#pragma unroll
  for (int i = 0; i < 4; ++i) {
#pragma unroll
    for (int j = 0; j < 4; ++j) v[i][j] *= iv;
    *(f32x4*)&ar[i * 256 + lane * 4] = v[i];
  }
}

// ---------------- dedicated PV: 512 blocks of 64 rows x 192 cols ----------------
__global__ __launch_bounds__(256) void pv_attn(
    const bf16* __restrict__ E, const bf16* __restrict__ VT,
    const float* __restrict__ part, bf16* __restrict__ ctx,
    float* __restrict__ attn) {
  __shared__ __attribute__((aligned(16))) bf16 aL[2 * 64 * 32];   // 8 KB
  __shared__ __attribute__((aligned(16))) bf16 bL[2 * 192 * 32];  // 24 KB
  __shared__ float ivL[64];
  const int tid = threadIdx.x;
  const int lane = tid & 63;
  const int wid = tid >> 6;
  const int wr = wid >> 1, wc = wid & 1;
  const int id = blockIdx.x;
  const int bz = id & 31;
  const int by = id >> 5;
  const int m0 = by * 64;
  const int b = bz >> 2, h = bz & 3;

  const bf16* Ab = E + ((long)bz << 20);
  const bf16* Bb = VT + (((long)(b * DM + h * HD)) << 10);

  if (tid < 64) {
    const float* p = part + ((((long)bz << 10) + m0 + tid) << 4);
    float s = 0.0f;
#pragma unroll
    for (int i = 0; i < 16; ++i) s += p[i];
    ivL[tid] = 1.0f / s;
  }
  __syncthreads();
  const float iv0 = ivL[tid >> 2];

  f32x4 acc[2][6] = {};
  const int rsel = lane & 15, ksel = (lane >> 4) * 8;

  for (int k0 = 0; k0 < SEQ; k0 += 64) {
#pragma unroll
    for (int h2 = 0; h2 < 2; ++h2) {
      {
        int f = tid * 8;
        int row = f >> 5, col = f & 31;
        gld_lds16(Ab + (long)(m0 + row) * SEQ + k0 + h2 * 32 + col, &aL[h2 * 2048 + f]);
      }
#pragma unroll
      for (int p = 0; p < 3; ++p) {
        int f = (p * 256 + tid) * 8;
        int row = f >> 5, col = f & 31;
        gld_lds16(Bb + (long)row * SEQ + k0 + h2 * 32 + col, &bL[h2 * 6144 + f]);
      }
    }
    __syncthreads();

    // MFMA first: keep matrix pipe fed; nt-stores drain behind it
#pragma unroll
    for (int h2 = 0; h2 < 2; ++h2) {
      bf16x8 af[2], bfr[6];
#pragma unroll
      for (int m = 0; m < 2; ++m)
        af[m] = *(const bf16x8*)&aL[h2 * 2048 + (wr * 32 + m * 16 + rsel) * 32 + ksel];
#pragma unroll
      for (int n = 0; n < 6; ++n)
        bfr[n] = *(const bf16x8*)&bL[h2 * 6144 + (wc * 96 + n * 16 + rsel) * 32 + ksel];
#pragma unroll
      for (int m = 0; m < 2; ++m)
#pragma unroll
        for (int n = 0; n < 6; ++n)
          acc[m][n] = __builtin_amdgcn_mfma_f32_16x16x32_bf16(af[m], bfr[n], acc[m][n], 0, 0, 0);
    }

    // attn f32 write from staged E (*inv), nontemporal
#pragma unroll
    for (int h2 = 0; h2 < 2; ++h2) {
      int f = tid * 8;
      int row = f >> 5, col = f & 31;
      bf16x8 e = *(const bf16x8*)&aL[h2 * 2048 + f];
      f32x4 w0, w1;
      w0[0] = (float)e[0] * iv0; w0[1] = (float)e[1] * iv0;
      w0[2] = (float)e[2] * iv0; w0[3] = (float)e[3] * iv0;
      w1[0] = (float)e[4] * iv0; w1[1] = (float)e[5] * iv0;
      w1[2] = (float)e[6] * iv0; w1[3] = (float)e[7] * iv0;
      float* ap = attn + ((long)bz << 20) + ((long)(m0 + row) << 10) + k0 + h2 * 32 + col;
      __builtin_nontemporal_store(w0, (f32x4*)ap);
      __builtin_nontemporal_store(w1, (f32x4*)(ap + 4));
    }
    __syncthreads();
  }

  const int rl = (lane >> 4) * 4, cl = lane & 15;
#pragma unroll
  for (int m = 0; m < 2; ++m)
#pragma unroll
    for (int n = 0; n < 6; ++n)
#pragma unroll
      for (int j = 0; j < 4; ++j) {
        int row = wr * 32 + m * 16 + rl + j;
        int col = wc * 96 + n * 16 + cl;
        bL[row * 192 + col] = (bf16)(acc[m][n][j] * ivL[row]);
      }
  __syncthreads();
#pragma unroll
  for (int it = 0; it < 6; ++it) {
    int idx2 = it * 256 + tid;
    int row = idx2 / 24;
    int col = (idx2 % 24) * 8;
    bf16x8 v = *(const bf16x8*)&bL[row * 192 + col];
    *(bf16x8*)&ctx[(long)(b * SEQ + m0 + row) * DM + h * HD + col] = v;
  }
}

// ---------------- GEMM (A row-major [M,K] bf16, BT row-major [N,K] bf16) ----------------
// BK=64 super-step (two [128][32] sub-buffers, ONE barrier pair).
// MODE 2: E = exp bf16 staged + row-partials (scores)
// MODE 7: fallback f32 E into attn
// MODE 5: PV fallback (A f32)
// MODE 4: final x f32, staged epilogue (+cb1+resid folded into coalesced write)
template <int MODE>
__global__ __launch_bounds__(256) void gemm_bt(
    const bf16* __restrict__ A, int lda,
    const bf16* __restrict__ BT, int ldb,
    const float* __restrict__ Af,
    int M, int N, int Kd,
    const float* __restrict__ cb1,
    const float* __restrict__ cb2,
    const float* __restrict__ resid,
    void* __restrict__ out, void* __restrict__ out2) {
  __shared__ __attribute__((aligned(16))) bf16 aL[2 * 128 * 32];
  __shared__ __attribute__((aligned(16))) bf16 bL[2 * 128 * 32];
  const int tid = threadIdx.x;
  const int lane = tid & 63;
  const int wid = tid >> 6;
  const int wr = wid >> 1, wc = wid & 1;
  int bx, by, bz;
  if constexpr (MODE == 2 || MODE == 7) {
    int idd = blockIdx.x;
    bz = idd & 31;
    int t = idd >> 5;
    bx = t & 7;
    by = t >> 3;
  } else if constexpr (MODE == 5) {
    int idd = blockIdx.x;
    bz = idd & 31;
    bx = (idd >> 5) & 1;
    by = idd >> 6;
  } else {
    int idd = blockIdx.x;
    by = idd & 63;
    bx = idd >> 6;
    bz = 0;
  }
  const int m0 = by * 128, n0 = bx * 128;

  const bf16* Ab = A;
  const bf16* Bb = BT;
  const float* Afb = Af;
  if constexpr (MODE == 2 || MODE == 7) {
    long o = ((long)((bz >> 2) * SEQ)) * DM + (long)(bz & 3) * HD;
    Ab = A + o;
    Bb = BT + o;
  }
  if constexpr (MODE == 5) {
    Bb = BT + (((long)((bz >> 2) * DM + (bz & 3) * HD)) << 10);
    Afb = Af + ((long)bz << 20);
  }

  f32x4 acc[4][4] = {};

  for (int k0 = 0; k0 < Kd; k0 += 64) {
#pragma unroll
    for (int h = 0; h < 2; ++h) {
      if constexpr (MODE == 5) {
#pragma unroll
        for (int p = 0; p < 2; ++p) {
          int f = (p * 256 + tid) * 8;
          int row = f >> 5, col = f & 31;
          const float* g = Afb + (long)(m0 + row) * lda + k0 + h * 32 + col;
          f32x4 x0 = *(const f32x4*)g;
          f32x4 x1 = *(const f32x4*)(g + 4);
          bf16x8 t;
          t[0] = (bf16)x0[0]; t[1] = (bf16)x0[1]; t[2] = (bf16)x0[2]; t[3] = (bf16)x0[3];
          t[4] = (bf16)x1[0]; t[5] = (bf16)x1[1]; t[6] = (bf16)x1[2]; t[7] = (bf16)x1[3];
          *(bf16x8*)&aL[h * 4096 + f] = t;
        }
      } else {
#pragma unroll
        for (int p = 0; p < 2; ++p) {
          int f = (p * 256 + tid) * 8;
          int row = f >> 5, col = f & 31;
          gld_lds16(Ab + (long)(m0 + row) * lda + k0 + h * 32 + col, &aL[h * 4096 + f]);
        }
      }
#pragma unroll
      for (int p = 0; p < 2; ++p) {
        int f = (p * 256 + tid) * 8;
        int row = f >> 5, col = f & 31;
        int nn = n0 + row;
        nn = nn < N ? nn : N - 1;
        gld_lds16(Bb + (long)nn * ldb + k0 + h * 32 + col, &bL[h * 4096 + f]);
      }
    }
    __syncthreads();

    const int rsel = lane & 15, ksel = (lane >> 4) * 8;
#pragma unroll
    for (int h = 0; h < 2; ++h) {
      bf16x8 af[4], bfr[4];
#pragma unroll
      for (int m = 0; m < 4; ++m)
        af[m] = *(const bf16x8*)&aL[h * 4096 + (wr * 64 + m * 16 + rsel) * 32 + ksel];
#pragma unroll
      for (int n = 0; n < 4; ++n)
        bfr[n] = *(const bf16x8*)&bL[h * 4096 + (wc * 64 + n * 16 + rsel) * 32 + ksel];
#pragma unroll
      for (int m = 0; m < 4; ++m)
#pragma unroll
        for (int n = 0; n < 4; ++n)
          acc[m][n] = __builtin_amdgcn_mfma_f32_16x16x32_bf16(af[m], bfr[n], acc[m][n], 0, 0, 0);
    }
    __syncthreads();
  }

  const int rl = (lane >> 4) * 4, cl = lane & 15;

  if constexpr (MODE == 2) {
    float bvv[4];
#pragma unroll
    for (int n = 0; n < 4; ++n)
      bvv[n] = cb2[(bz << 10) + n0 + wc * 64 + n * 16 + cl];
#pragma unroll
    for (int m = 0; m < 4; ++m)
#pragma unroll
      for (int n = 0; n < 4; ++n)
#pragma unroll
        for (int j = 0; j < 4; ++j)
          acc[m][n][j] = __expf(fmaf(acc[m][n][j], SCALE, bvv[n]));
    float* part = (float*)out2;
#pragma unroll
    for (int m = 0; m < 4; ++m) {
#pragma unroll
      for (int j = 0; j < 4; ++j) {
        float s = acc[m][0][j] + acc[m][1][j] + acc[m][2][j] + acc[m][3][j];
#pragma unroll
        for (int d = 1; d < 16; d <<= 1) s += __shfl_xor(s, d);
        if (cl == 0) {
          int mg = m0 + wr * 64 + m * 16 + rl + j;
          part[((((long)bz << 10) + mg) << 4) + bx * 2 + wc] = s;
        }
      }
    }
#pragma unroll
    for (int m = 0; m < 4; ++m)
#pragma unroll
      for (int n = 0; n < 4; ++n)
#pragma unroll
        for (int j = 0; j < 4; ++j) {
          int row = wr * 64 + m * 16 + rl + j;
          int col = wc * 64 + n * 16 + cl;
          bf16* Lt = (row < 64) ? &aL[row * 128 + col] : &bL[(row - 64) * 128 + col];
          *Lt = (bf16)acc[m][n][j];
        }
    __syncthreads();
#pragma unroll
    for (int it = 0; it < 8; ++it) {
      int row = it * 16 + (tid >> 4);
      int col = (tid & 15) * 8;
      bf16x8 v = (row < 64) ? *(const bf16x8*)&aL[row * 128 + col]
                            : *(const bf16x8*)&bL[(row - 64) * 128 + col];
      *(bf16x8*)&((bf16*)out)[((long)bz << 20) + ((long)(m0 + row) << 10) + n0 + col] = v;
    }
    return;
  }

  if constexpr (MODE == 4) {
#pragma unroll
    for (int half = 0; half < 2; ++half) {
      if (wr == half) {
#pragma unroll
        for (int m = 0; m < 4; ++m)
#pragma unroll
          for (int n = 0; n < 4; ++n)
#pragma unroll
            for (int j = 0; j < 4; ++j) {
              int r = m * 16 + rl + j;
              int col = wc * 64 + n * 16 + cl;
              float* Lf = (r < 32) ? (float*)aL + r * 128
                                   : (float*)bL + (r - 32) * 128;
              Lf[col] = acc[m][n][j];
            }
      }
      __syncthreads();
#pragma unroll
      for (int it = 0; it < 8; ++it) {
        int r = it * 8 + (tid >> 5);
        int c = (tid & 31) * 4;
        const float* Lf = (r < 32) ? (const float*)aL + r * 128
                                   : (const float*)bL + (r - 32) * 128;
        f32x4 v = *(const f32x4*)&Lf[c];
        long o = (long)(m0 + half * 64 + r) * DM + n0 + c;
        f32x4 rs = *(const f32x4*)&resid[o];
        f32x4 y;
        y[0] = v[0] + cb1[n0 + c] + rs[0];
        y[1] = v[1] + cb1[n0 + c + 1] + rs[1];
        y[2] = v[2] + cb1[n0 + c + 2] + rs[2];
        y[3] = v[3] + cb1[n0 + c + 3] + rs[3];
        *(f32x4*)&((float*)out)[o] = y;
      }
      __syncthreads();
    }
    return;
  }

#pragma unroll
  for (int m = 0; m < 4; ++m) {
#pragma unroll
    for (int n = 0; n < 4; ++n) {
      int ng = n0 + wc * 64 + n * 16 + cl;
      if (ng >= N) continue;
#pragma unroll
      for (int j = 0; j < 4; ++j) {
        int mg = m0 + wr * 64 + m * 16 + rl + j;
        float v = acc[m][n][j];
        if constexpr (MODE == 7) {
          ((float*)out)[((long)bz << 20) + ((long)mg << 10) + ng] =
              __expf(fmaf(v, SCALE, cb2[(bz << 10) + ng]));
        } else if constexpr (MODE == 5) {
          ((bf16*)out)[(long)((bz >> 2) * SEQ + mg) * DM + (bz & 3) * HD + ng] = (bf16)v;
        }
      }
    }
  }
}

// ---------------- layernorm (one wave per row of 768, in place) ----------------
__global__ __launch_bounds__(256) void layernorm_rows(float* x, const float* __restrict__ gam,
                                                      const float* __restrict__ bet) {
  int row = blockIdx.x * 4 + (threadIdx.x >> 6);
  int lane = threadIdx.x & 63;
  float* r = x + (long)row * DM;
  f32x4 v[3];
#pragma unroll
  for (int i = 0; i < 3; ++i) v[i] = *(const f32x4*)&r[i * 256 + lane * 4];
  float s = 0.0f, ss = 0.0f;
#pragma unroll
  for (int i = 0; i < 3; ++i)
#pragma unroll
    for (int j = 0; j < 4; ++j) {
      s += v[i][j];
      ss += v[i][j] * v[i][j];
    }
  for (int d = 1; d < 64; d <<= 1) {
    s += __shfl_xor(s, d);
    ss += __shfl_xor(ss, d);
  }
  float mu = s * (1.0f / 768.0f);
  float var = ss * (1.0f / 768.0f) - mu * mu;
  float rs = 1.0f / sqrtf(var + 1e-5f);
#pragma unroll
  for (int i = 0; i < 3; ++i) {
#pragma unroll
    for (int j = 0; j < 4; ++j) {
      int c = i * 256 + lane * 4 + j;
      v[i][j] = (v[i][j] - mu) * rs * gam[c] + bet[c];
    }
    *(f32x4*)&r[i * 256 + lane * 4] = v[i];
  }
}

// ---------------- launcher ----------------
extern "C" void kernel_launch(void* const* d_in, const int* in_sizes, int n_in,
                              void* d_out, int out_size, void* d_ws, size_t ws_size,
                              hipStream_t stream) {
  const float* Xd = (const float*)d_in[0];
  const float* Xb = (const float*)d_in[1];
  const float* Wq = (const float*)d_in[2];
  const float* bq = (const float*)d_in[3];
  const float* Wk = (const float*)d_in[4];
  const float* bk = (const float*)d_in[5];
  const float* Wv = (const float*)d_in[6];
  const float* bv = (const float*)d_in[7];
  const float* Wb1 = (const float*)d_in[8];
  const float* bb1 = (const float*)d_in[9];
  const float* Wb2 = (const float*)d_in[10];
  const float* bb2 = (const float*)d_in[11];
  const float* Wo = (const float*)d_in[12];
  const float* bo = (const float*)d_in[13];
  const float* lng = (const float*)d_in[14];
  const float* lnb = (const float*)d_in[15];

  float* y = (float*)d_out;                  // 8192*768 f32
  float* attn = y + (long)MROWS * DM;        // 32*1024*1024 f32

  char* w = (char*)d_ws;
  bf16* Xd_bf = (bf16*)w; w += (long)MROWS * DM * 2;   // later reused as ctx
  bf16* Xb_bf = (bf16*)w; w += (long)MROWS * DB * 2;
  bf16* WqvT = (bf16*)w; w += (long)2 * DM * DM * 2;   // [1536][768]
  bf16* WkT = (bf16*)w; w += (long)DM * DB * 2;
  bf16* WoT = (bf16*)w; w += (long)DM * DM * 2;
  bf16* Qb = (bf16*)w; w += (long)MROWS * DM * 2;
  bf16* Kb = (bf16*)w; w += (long)MROWS * DM * 2;
  bf16* VTb = (bf16*)w; w += (long)MROWS * DM * 2;
  float* biasarr = (float*)w; w += (long)BATCH * NHEADS * SEQ * 4;
  float* part = (float*)w; w += (long)32 * SEQ * 16 * 4;   // 2 MB partials
  bf16* Sb = (bf16*)w; w += (long)32 * SEQ * SEQ * 2;      // 64 MB E buffer
  const bool useS = ((size_t)(w - (char*)d_ws)) <= ws_size;
  bf16* ctxb = Xd_bf;  // Xd_bf dead after QV projection; reuse for ctx

  dim3 blk(256);
  // fused prologue: cvt Xd, cvt Xb, bias MLP, tiled weight transposes
  prologue<<<7132, blk, 0, stream>>>(Xd, Xd_bf, Xb, Xb_bf, Wq, Wv, Wk, Wo,
                                     WqvT, WqvT + (long)DM * DM, WkT, WoT,
                                     Wb1, bb1, Wb2, bb2, biasarr);

  // K + [Q|V] projections in one dispatch
  proj_all<<<1152, blk, 0, stream>>>(Xb_bf, WkT, Xd_bf, WqvT, bk, bq, bv, Kb, Qb, VTb);

  if (useS) {
    // E = exp(QK^T*scale + bias) bf16 (staged coalesced) + row-partials
    gemm_bt<2><<<2048, blk, 0, stream>>>(Qb, DM, Kb, DM, nullptr, SEQ, SEQ, HD,
                                         nullptr, biasarr, nullptr, Sb, part);
    // PV: 64x192 blocks, E staged once, attn written in k-loop, ctx staged
    pv_attn<<<512, blk, 0, stream>>>(Sb, VTb, part, ctxb, attn);
  } else {
    gemm_bt<7><<<2048, blk, 0, stream>>>(Qb, DM, Kb, DM, nullptr, SEQ, SEQ, HD,
                                         nullptr, biasarr, nullptr, attn, nullptr);
    rowsum_scale_f32<<<8192, blk, 0, stream>>>(attn);
    gemm_bt<5><<<512, blk, 0, stream>>>(nullptr, SEQ, VTb, SEQ, attn, SEQ, HD, SEQ,
                                        nullptr, nullptr, nullptr, ctxb, nullptr);
  }
  // x = ctx @ Wo + bo + resid -> y region (staged f32 epilogue), then LN in place
  gemm_bt<4><<<384, blk, 0, stream>>>(ctxb, DM, WoT, DM, nullptr, MROWS, DM, DM,
                                      bo, nullptr, Xd, y, nullptr);
  layernorm_rows<<<2048, 256, 0, stream>>>(y, lng, lnb);
}

// Round 22
// 168.082 us; speedup vs baseline: 1.0863x; 1.0056x over previous
//
#include <hip/hip_runtime.h>
#include <hip/hip_bf16.h>
#include <math.h>
#include <stdint.h>

typedef __bf16 bf16;
typedef __bf16 bf16x8 __attribute__((ext_vector_type(8)));
typedef __bf16 bf16x4v __attribute__((ext_vector_type(4)));
typedef float f32x4 __attribute__((ext_vector_type(4)));

#define NHEADS 4
#define DM 768
#define DB 64
#define HD 192
#define BATCH 8
#define SEQ 1024
#define MROWS 8192
#define SCALE 0.07216878364870323f

__device__ __forceinline__ void gld_lds16(const void* g, void* l) {
  __builtin_amdgcn_global_load_lds(
      (__attribute__((address_space(1))) void*)(void*)g,
      (__attribute__((address_space(3))) void*)l, 16, 0, 0);
}

// ---------------- fused prologue: cvt Xd, cvt Xb, bias MLP, tiled weight transposes ----------------
__global__ __launch_bounds__(256) void prologue(
    const float* __restrict__ Xd, bf16* __restrict__ Xd_bf,
    const float* __restrict__ Xb, bf16* __restrict__ Xb_bf,
    const float* __restrict__ Wq, const float* __restrict__ Wv,
    const float* __restrict__ Wk, const float* __restrict__ Wo,
    bf16* __restrict__ WT0, bf16* __restrict__ WT1,
    bf16* __restrict__ WT2, bf16* __restrict__ WT3,
    const float* __restrict__ Wb1, const float* __restrict__ bb1,
    const float* __restrict__ Wb2, const float* __restrict__ bb2,
    float* __restrict__ biasarr) {
  __shared__ float Lt[64 * 65];
  const int id = blockIdx.x;
  const int tid = threadIdx.x;
  if (id < 6656) {
    const float* in = (id < 6144) ? Xd : Xb;
    bf16* out = (id < 6144) ? Xd_bf : Xb_bf;
    long i = (long)(id < 6144 ? id : id - 6144) * 256 + tid;
    f32x4 v = *(const f32x4*)&in[i * 4];
    bf16x4v t;
    t[0] = (bf16)v[0]; t[1] = (bf16)v[1]; t[2] = (bf16)v[2]; t[3] = (bf16)v[3];
    *(bf16x4v*)&out[i * 4] = t;
  } else if (id < 6688) {
    int idx = (id - 6656) * 256 + tid;
    const float* x = Xb + (long)idx * DB;
    float h[8];
#pragma unroll
    for (int j = 0; j < 8; ++j) h[j] = bb1[j];
    for (int k = 0; k < DB; ++k) {
      float xv = x[k];
#pragma unroll
      for (int j = 0; j < 8; ++j) h[j] = fmaf(xv, Wb1[k * 8 + j], h[j]);
    }
#pragma unroll
    for (int j = 0; j < 8; ++j) {
      float a = h[j];
      h[j] = 0.5f * a * (1.0f + erff(a * 0.7071067811865476f));
    }
    int b = idx >> 10, s = idx & 1023;
#pragma unroll
    for (int o = 0; o < 4; ++o) {
      float a = bb2[o];
#pragma unroll
      for (int j = 0; j < 8; ++j) a = fmaf(h[j], Wb2[j * 4 + o], a);
      biasarr[((long)(b * 4 + o) << 10) + s] = a;
    }
  } else {
    int wi = id - 6688;
    const float* W;
    bf16* WT;
    int K, tIdx;
    if (wi < 144)      { W = Wq; WT = WT0; K = DM; tIdx = wi; }
    else if (wi < 288) { W = Wv; WT = WT1; K = DM; tIdx = wi - 144; }
    else if (wi < 300) { W = Wk; WT = WT2; K = DB; tIdx = wi - 288; }
    else               { W = Wo; WT = WT3; K = DM; tIdx = wi - 300; }
    const int tk0 = (tIdx / 12) * 64;
    const int tn0 = (tIdx % 12) * 64;
#pragma unroll
    for (int p = 0; p < 4; ++p) {
      int r = p * 16 + (tid >> 4);
      int c = (tid & 15) * 4;
      f32x4 v = *(const f32x4*)&W[(long)(tk0 + r) * DM + tn0 + c];
      Lt[r * 65 + c] = v[0]; Lt[r * 65 + c + 1] = v[1];
      Lt[r * 65 + c + 2] = v[2]; Lt[r * 65 + c + 3] = v[3];
    }
    __syncthreads();
    const int n = tid >> 2, kg = (tid & 3) * 16;
    bf16x8 o0, o1;
#pragma unroll
    for (int e = 0; e < 8; ++e) {
      o0[e] = (bf16)Lt[(kg + e) * 65 + n];
      o1[e] = (bf16)Lt[(kg + 8 + e) * 65 + n];
    }
    *(bf16x8*)&WT[(long)(tn0 + n) * K + tk0 + kg] = o0;
    *(bf16x8*)&WT[(long)(tn0 + n) * K + tk0 + kg + 8] = o1;
  }
}

// ---------------- unified projections: K (384 blocks, Kd=64) + QV (768 blocks) ----------------
__global__ __launch_bounds__(256) void proj_all(
    const bf16* __restrict__ Xb_bf, const bf16* __restrict__ WkT,
    const bf16* __restrict__ Xd_bf, const bf16* __restrict__ WqvT,
    const float* __restrict__ bk, const float* __restrict__ bq,
    const float* __restrict__ bv,
    bf16* __restrict__ Kb, bf16* __restrict__ Qb, bf16* __restrict__ VTb) {
  __shared__ __attribute__((aligned(16))) bf16 aL[2 * 128 * 32];
  __shared__ __attribute__((aligned(16))) bf16 bL[2 * 128 * 32];
  const int tid = threadIdx.x;
  const int lane = tid & 63;
  const int wid = tid >> 6;
  const int wr = wid >> 1, wc = wid & 1;
  const int id = blockIdx.x;
  const bool isK = id < 384;
  int by, bx, lda, Kd, N;
  const bf16 *A, *BT;
  if (isK) {
    by = id & 63; bx = id >> 6;
    A = Xb_bf; BT = WkT; lda = DB; Kd = DB; N = DM;
  } else {
    int t = id - 384;
    by = t & 63; bx = t >> 6;
    A = Xd_bf; BT = WqvT; lda = DM; Kd = DM; N = 2 * DM;
  }
  const int m0 = by * 128, n0 = bx * 128;

  f32x4 acc[4][4] = {};

  for (int k0 = 0; k0 < Kd; k0 += 64) {
#pragma unroll
    for (int h = 0; h < 2; ++h) {
#pragma unroll
      for (int p = 0; p < 2; ++p) {
        int f = (p * 256 + tid) * 8;
        int row = f >> 5, col = f & 31;
        gld_lds16(A + (long)(m0 + row) * lda + k0 + h * 32 + col, &aL[h * 4096 + f]);
      }
#pragma unroll
      for (int p = 0; p < 2; ++p) {
        int f = (p * 256 + tid) * 8;
        int row = f >> 5, col = f & 31;
        int nn = n0 + row;
        nn = nn < N ? nn : N - 1;
        gld_lds16(BT + (long)nn * lda + k0 + h * 32 + col, &bL[h * 4096 + f]);
      }
    }
    __syncthreads();

    const int rsel = lane & 15, ksel = (lane >> 4) * 8;
#pragma unroll
    for (int h = 0; h < 2; ++h) {
      bf16x8 af[4], bfr[4];
#pragma unroll
      for (int m = 0; m < 4; ++m)
        af[m] = *(const bf16x8*)&aL[h * 4096 + (wr * 64 + m * 16 + rsel) * 32 + ksel];
#pragma unroll
      for (int n = 0; n < 4; ++n)
        bfr[n] = *(const bf16x8*)&bL[h * 4096 + (wc * 64 + n * 16 + rsel) * 32 + ksel];
#pragma unroll
      for (int m = 0; m < 4; ++m)
#pragma unroll
        for (int n = 0; n < 4; ++n)
          acc[m][n] = __builtin_amdgcn_mfma_f32_16x16x32_bf16(af[m], bfr[n], acc[m][n], 0, 0, 0);
    }
    __syncthreads();
  }

  const int rl = (lane >> 4) * 4, cl = lane & 15;

  if (!isK && n0 >= DM) {
    const int d0 = n0 - DM;
    float bvv[4];
#pragma unroll
    for (int n = 0; n < 4; ++n)
      bvv[n] = bv[d0 + wc * 64 + n * 16 + cl];
#pragma unroll
    for (int m = 0; m < 4; ++m)
#pragma unroll
      for (int n = 0; n < 4; ++n)
#pragma unroll
        for (int j = 0; j < 4; ++j) {
          int row = wr * 64 + m * 16 + rl + j;
          int col = wc * 64 + n * 16 + cl;
          int sw = row ^ ((col & 7) << 4);
          bf16 val = (bf16)(acc[m][n][j] + bvv[n]);
          if (col < 64) aL[col * 128 + sw] = val;
          else          bL[(col - 64) * 128 + sw] = val;
        }
    __syncthreads();
    const int b = m0 >> 10, s0 = m0 & 1023;
#pragma unroll
    for (int it = 0; it < 8; ++it) {
      int d = it * 16 + (tid >> 4);
      int s = (tid & 15) * 8;
      int sw = s ^ ((d & 7) << 4);
      bf16x8 v = (d < 64) ? *(const bf16x8*)&aL[d * 128 + sw]
                          : *(const bf16x8*)&bL[(d - 64) * 128 + sw];
      *(bf16x8*)&VTb[((long)(b * DM + d0 + d) << 10) + s0 + s] = v;
    }
    return;
  }

  const float* cb = isK ? bk : bq;
  bf16* out = isK ? Kb : Qb;
  float bvv[4];
#pragma unroll
  for (int n = 0; n < 4; ++n)
    bvv[n] = cb[n0 + wc * 64 + n * 16 + cl];
#pragma unroll
  for (int m = 0; m < 4; ++m)
#pragma unroll
    for (int n = 0; n < 4; ++n)
#pragma unroll
      for (int j = 0; j < 4; ++j) {
        int row = wr * 64 + m * 16 + rl + j;
        int col = wc * 64 + n * 16 + cl;
        bf16 val = (bf16)(acc[m][n][j] + bvv[n]);
        if (row < 64) aL[row * 128 + col] = val;
        else          bL[(row - 64) * 128 + col] = val;
      }
  __syncthreads();
#pragma unroll
  for (int it = 0; it < 8; ++it) {
    int row = it * 16 + (tid >> 4);
    int col = (tid & 15) * 8;
    bf16x8 v = (row < 64) ? *(const bf16x8*)&aL[row * 128 + col]
                          : *(const bf16x8*)&bL[(row - 64) * 128 + col];
    *(bf16x8*)&out[(long)(m0 + row) * DM + n0 + col] = v;
  }
}

// fallback: E was written f32 into attn; normalize in place.
__global__ __launch_bounds__(256) void rowsum_scale_f32(float* __restrict__ attn) {
  const int row = blockIdx.x * 4 + (threadIdx.x >> 6);
  const int lane = threadIdx.x & 63;
  float* ar = attn + ((long)row << 10);
  f32x4 v[4];
#pragma unroll
  for (int i = 0; i < 4; ++i) v[i] = *(const f32x4*)&ar[i * 256 + lane * 4];
  float s = 0.0f;
#pragma unroll
  for (int i = 0; i < 4; ++i)
#pragma unroll
    for (int j = 0; j < 4; ++j) s += v[i][j];
  for (int d = 1; d < 64; d <<= 1) s += __shfl_xor(s, d);
  float iv = 1.0f / s;
#pragma unroll
  for (int i = 0; i < 4; ++i) {
#pragma unroll
    for (int j = 0; j < 4; ++j) v[i][j] *= iv;
    *(f32x4*)&ar[i * 256 + lane * 4] = v[i];
  }
}

// ---------------- dedicated PV: 512 blocks of 64 rows x 192 cols ----------------
__global__ __launch_bounds__(256) void pv_attn(
    const bf16* __restrict__ E, const bf16* __restrict__ VT,
    const float* __restrict__ part, bf16* __restrict__ ctx,
    float* __restrict__ attn) {
  __shared__ __attribute__((aligned(16))) bf16 aL[2 * 64 * 32];   // 8 KB
  __shared__ __attribute__((aligned(16))) bf16 bL[2 * 192 * 32];  // 24 KB
  __shared__ float ivL[64];
  const int tid = threadIdx.x;
  const int lane = tid & 63;
  const int wid = tid >> 6;
  const int wr = wid >> 1, wc = wid & 1;
  const int id = blockIdx.x;
  const int bz = id & 31;
  const int by = id >> 5;
  const int m0 = by * 64;
  const int b = bz >> 2, h = bz & 3;

  const bf16* Ab = E + ((long)bz << 20);
  const bf16* Bb = VT + (((long)(b * DM + h * HD)) << 10);

  if (tid < 64) {
    const float* p = part + ((((long)bz << 10) + m0 + tid) << 4);
    float s = 0.0f;
#pragma unroll
    for (int i = 0; i < 16; ++i) s += p[i];
    ivL[tid] = 1.0f / s;
  }
  __syncthreads();
  const float iv0 = ivL[tid >> 2];

  f32x4 acc[2][6] = {};
  const int rsel = lane & 15, ksel = (lane >> 4) * 8;

  for (int k0 = 0; k0 < SEQ; k0 += 64) {
#pragma unroll
    for (int h2 = 0; h2 < 2; ++h2) {
      {
        int f = tid * 8;
        int row = f >> 5, col = f & 31;
        gld_lds16(Ab + (long)(m0 + row) * SEQ + k0 + h2 * 32 + col, &aL[h2 * 2048 + f]);
      }
#pragma unroll
      for (int p = 0; p < 3; ++p) {
        int f = (p * 256 + tid) * 8;
        int row = f >> 5, col = f & 31;
        gld_lds16(Bb + (long)row * SEQ + k0 + h2 * 32 + col, &bL[h2 * 6144 + f]);
      }
    }
    __syncthreads();

    // MFMA first: keep matrix pipe fed; nt-stores drain behind it
#pragma unroll
    for (int h2 = 0; h2 < 2; ++h2) {
      bf16x8 af[2], bfr[6];
#pragma unroll
      for (int m = 0; m < 2; ++m)
        af[m] = *(const bf16x8*)&aL[h2 * 2048 + (wr * 32 + m * 16 + rsel) * 32 + ksel];
#pragma unroll
      for (int n = 0; n < 6; ++n)
        bfr[n] = *(const bf16x8*)&bL[h2 * 6144 + (wc * 96 + n * 16 + rsel) * 32 + ksel];
#pragma unroll
      for (int m = 0; m < 2; ++m)
#pragma unroll
        for (int n = 0; n < 6; ++n)
          acc[m][n] = __builtin_amdgcn_mfma_f32_16x16x32_bf16(af[m], bfr[n], acc[m][n], 0, 0, 0);
    }

    // attn f32 write from staged E (*inv), nontemporal
#pragma unroll
    for (int h2 = 0; h2 < 2; ++h2) {
      int f = tid * 8;
      int row = f >> 5, col = f & 31;
      bf16x8 e = *(const bf16x8*)&aL[h2 * 2048 + f];
      f32x4 w0, w1;
      w0[0] = (float)e[0] * iv0; w0[1] = (float)e[1] * iv0;
      w0[2] = (float)e[2] * iv0; w0[3] = (float)e[3] * iv0;
      w1[0] = (float)e[4] * iv0; w1[1] = (float)e[5] * iv0;
      w1[2] = (float)e[6] * iv0; w1[3] = (float)e[7] * iv0;
      float* ap = attn + ((long)bz << 20) + ((long)(m0 + row) << 10) + k0 + h2 * 32 + col;
      __builtin_nontemporal_store(w0, (f32x4*)ap);
      __builtin_nontemporal_store(w1, (f32x4*)(ap + 4));
    }
    __syncthreads();
  }

  const int rl = (lane >> 4) * 4, cl = lane & 15;
#pragma unroll
  for (int m = 0; m < 2; ++m)
#pragma unroll
    for (int n = 0; n < 6; ++n)
#pragma unroll
      for (int j = 0; j < 4; ++j) {
        int row = wr * 32 + m * 16 + rl + j;
        int col = wc * 96 + n * 16 + cl;
        bL[row * 192 + col] = (bf16)(acc[m][n][j] * ivL[row]);
      }
  __syncthreads();
#pragma unroll
  for (int it = 0; it < 6; ++it) {
    int idx2 = it * 256 + tid;
    int row = idx2 / 24;
    int col = (idx2 % 24) * 8;
    bf16x8 v = *(const bf16x8*)&bL[row * 192 + col];
    *(bf16x8*)&ctx[(long)(b * SEQ + m0 + row) * DM + h * HD + col] = v;
  }
}

// ---------------- dedicated final GEMM: 768 blocks of 64 rows x 128 cols ----------------
// x = ctx @ Wo + bo + resid; balanced 3 blocks/CU; staged f32 epilogue.
__global__ __launch_bounds__(256) void final_gemm(
    const bf16* __restrict__ A, const bf16* __restrict__ BT,
    const float* __restrict__ bo, const float* __restrict__ resid,
    float* __restrict__ out) {
  __shared__ __attribute__((aligned(16))) bf16 aL[2 * 64 * 32];   // 8 KB
  __shared__ __attribute__((aligned(16))) bf16 bL[2 * 128 * 32];  // 16 KB
  const int tid = threadIdx.x;
  const int lane = tid & 63;
  const int wid = tid >> 6;
  const int wr = wid >> 1, wc = wid & 1;   // rows: wr*32; cols: wc*64
  const int id = blockIdx.x;
  const int by = id & 127;   // same-A-panel blocks differ by 128 (==0 mod 8 -> same XCD)
  const int bx = id >> 7;    // 0..5
  const int m0 = by * 64, n0 = bx * 128;

  f32x4 acc[2][4] = {};
  const int rsel = lane & 15, ksel = (lane >> 4) * 8;

  for (int k0 = 0; k0 < DM; k0 += 64) {
#pragma unroll
    for (int h = 0; h < 2; ++h) {
      {
        int f = tid * 8;
        int row = f >> 5, col = f & 31;
        gld_lds16(A + (long)(m0 + row) * DM + k0 + h * 32 + col, &aL[h * 2048 + f]);
      }
#pragma unroll
      for (int p = 0; p < 2; ++p) {
        int f = (p * 256 + tid) * 8;
        int row = f >> 5, col = f & 31;
        gld_lds16(BT + (long)(n0 + row) * DM + k0 + h * 32 + col, &bL[h * 4096 + f]);
      }
    }
    __syncthreads();

#pragma unroll
    for (int h = 0; h < 2; ++h) {
      bf16x8 af[2], bfr[4];
#pragma unroll
      for (int m = 0; m < 2; ++m)
        af[m] = *(const bf16x8*)&aL[h * 2048 + (wr * 32 + m * 16 + rsel) * 32 + ksel];
#pragma unroll
      for (int n = 0; n < 4; ++n)
        bfr[n] = *(const bf16x8*)&bL[h * 4096 + (wc * 64 + n * 16 + rsel) * 32 + ksel];
#pragma unroll
      for (int m = 0; m < 2; ++m)
#pragma unroll
        for (int n = 0; n < 4; ++n)
          acc[m][n] = __builtin_amdgcn_mfma_f32_16x16x32_bf16(af[m], bfr[n], acc[m][n], 0, 0, 0);
    }
    __syncthreads();
  }

  // staged f32 epilogue: two 32-row halves through bL (16 KB = [32][128] f32)
  const int rl = (lane >> 4) * 4, cl = lane & 15;
#pragma unroll
  for (int half = 0; half < 2; ++half) {
    if (wr == half) {
#pragma unroll
      for (int m = 0; m < 2; ++m)
#pragma unroll
        for (int n = 0; n < 4; ++n)
#pragma unroll
          for (int j = 0; j < 4; ++j) {
            int r = m * 16 + rl + j;             // 0..31
            int col = wc * 64 + n * 16 + cl;
            ((float*)bL)[r * 128 + col] = acc[m][n][j];
          }
    }
    __syncthreads();
#pragma unroll
    for (int it = 0; it < 4; ++it) {
      int r = it * 8 + (tid >> 5);
      int c = (tid & 31) * 4;
      f32x4 v = *(const f32x4*)&((const float*)bL)[r * 128 + c];
      long o = (long)(m0 + half * 32 + r) * DM + n0 + c;
      f32x4 rs = *(const f32x4*)&resid[o];
      f32x4 y;
      y[0] = v[0] + bo[n0 + c] + rs[0];
      y[1] = v[1] + bo[n0 + c + 1] + rs[1];
      y[2] = v[2] + bo[n0 + c + 2] + rs[2];
      y[3] = v[3] + bo[n0 + c + 3] + rs[3];
      *(f32x4*)&out[o] = y;
    }
    __syncthreads();
  }
}

// ---------------- GEMM (A row-major [M,K] bf16, BT row-major [N,K] bf16) ----------------
// BK=64 super-step. MODE 2: E = exp bf16 staged + row-partials (scores)
// MODE 7: fallback f32 E into attn ; MODE 5: PV fallback (A f32)
template <int MODE>
__global__ __launch_bounds__(256) void gemm_bt(
    const bf16* __restrict__ A, int lda,
    const bf16* __restrict__ BT, int ldb,
    const float* __restrict__ Af,
    int M, int N, int Kd,
    const float* __restrict__ cb1,
    const float* __restrict__ cb2,
    const float* __restrict__ resid,
    void* __restrict__ out, void* __restrict__ out2) {
  __shared__ __attribute__((aligned(16))) bf16 aL[2 * 128 * 32];
  __shared__ __attribute__((aligned(16))) bf16 bL[2 * 128 * 32];
  const int tid = threadIdx.x;
  const int lane = tid & 63;
  const int wid = tid >> 6;
  const int wr = wid >> 1, wc = wid & 1;
  int bx, by, bz;
  if constexpr (MODE == 2 || MODE == 7) {
    int idd = blockIdx.x;
    bz = idd & 31;
    int t = idd >> 5;
    bx = t & 7;
    by = t >> 3;
  } else {
    int idd = blockIdx.x;
    bz = idd & 31;
    bx = (idd >> 5) & 1;
    by = idd >> 6;
  }
  const int m0 = by * 128, n0 = bx * 128;

  const bf16* Ab = A;
  const bf16* Bb = BT;
  const float* Afb = Af;
  if constexpr (MODE == 2 || MODE == 7) {
    long o = ((long)((bz >> 2) * SEQ)) * DM + (long)(bz & 3) * HD;
    Ab = A + o;
    Bb = BT + o;
  }
  if constexpr (MODE == 5) {
    Bb = BT + (((long)((bz >> 2) * DM + (bz & 3) * HD)) << 10);
    Afb = Af + ((long)bz << 20);
  }

  f32x4 acc[4][4] = {};

  for (int k0 = 0; k0 < Kd; k0 += 64) {
#pragma unroll
    for (int h = 0; h < 2; ++h) {
      if constexpr (MODE == 5) {
#pragma unroll
        for (int p = 0; p < 2; ++p) {
          int f = (p * 256 + tid) * 8;
          int row = f >> 5, col = f & 31;
          const float* g = Afb + (long)(m0 + row) * lda + k0 + h * 32 + col;
          f32x4 x0 = *(const f32x4*)g;
          f32x4 x1 = *(const f32x4*)(g + 4);
          bf16x8 t;
          t[0] = (bf16)x0[0]; t[1] = (bf16)x0[1]; t[2] = (bf16)x0[2]; t[3] = (bf16)x0[3];
          t[4] = (bf16)x1[0]; t[5] = (bf16)x1[1]; t[6] = (bf16)x1[2]; t[7] = (bf16)x1[3];
          *(bf16x8*)&aL[h * 4096 + f] = t;
        }
      } else {
#pragma unroll
        for (int p = 0; p < 2; ++p) {
          int f = (p * 256 + tid) * 8;
          int row = f >> 5, col = f & 31;
          gld_lds16(Ab + (long)(m0 + row) * lda + k0 + h * 32 + col, &aL[h * 4096 + f]);
        }
      }
#pragma unroll
      for (int p = 0; p < 2; ++p) {
        int f = (p * 256 + tid) * 8;
        int row = f >> 5, col = f & 31;
        int nn = n0 + row;
        nn = nn < N ? nn : N - 1;
        gld_lds16(Bb + (long)nn * ldb + k0 + h * 32 + col, &bL[h * 4096 + f]);
      }
    }
    __syncthreads();

    const int rsel = lane & 15, ksel = (lane >> 4) * 8;
#pragma unroll
    for (int h = 0; h < 2; ++h) {
      bf16x8 af[4], bfr[4];
#pragma unroll
      for (int m = 0; m < 4; ++m)
        af[m] = *(const bf16x8*)&aL[h * 4096 + (wr * 64 + m * 16 + rsel) * 32 + ksel];
#pragma unroll
      for (int n = 0; n < 4; ++n)
        bfr[n] = *(const bf16x8*)&bL[h * 4096 + (wc * 64 + n * 16 + rsel) * 32 + ksel];
#pragma unroll
      for (int m = 0; m < 4; ++m)
#pragma unroll
        for (int n = 0; n < 4; ++n)
          acc[m][n] = __builtin_amdgcn_mfma_f32_16x16x32_bf16(af[m], bfr[n], acc[m][n], 0, 0, 0);
    }
    __syncthreads();
  }

  const int rl = (lane >> 4) * 4, cl = lane & 15;

  if constexpr (MODE == 2) {
    float bvv[4];
#pragma unroll
    for (int n = 0; n < 4; ++n)
      bvv[n] = cb2[(bz << 10) + n0 + wc * 64 + n * 16 + cl];
#pragma unroll
    for (int m = 0; m < 4; ++m)
#pragma unroll
      for (int n = 0; n < 4; ++n)
#pragma unroll
        for (int j = 0; j < 4; ++j)
          acc[m][n][j] = __expf(fmaf(acc[m][n][j], SCALE, bvv[n]));
    float* part = (float*)out2;
#pragma unroll
    for (int m = 0; m < 4; ++m) {
#pragma unroll
      for (int j = 0; j < 4; ++j) {
        float s = acc[m][0][j] + acc[m][1][j] + acc[m][2][j] + acc[m][3][j];
#pragma unroll
        for (int d = 1; d < 16; d <<= 1) s += __shfl_xor(s, d);
        if (cl == 0) {
          int mg = m0 + wr * 64 + m * 16 + rl + j;
          part[((((long)bz << 10) + mg) << 4) + bx * 2 + wc] = s;
        }
      }
    }
#pragma unroll
    for (int m = 0; m < 4; ++m)
#pragma unroll
      for (int n = 0; n < 4; ++n)
#pragma unroll
        for (int j = 0; j < 4; ++j) {
          int row = wr * 64 + m * 16 + rl + j;
          int col = wc * 64 + n * 16 + cl;
          bf16* Lt = (row < 64) ? &aL[row * 128 + col] : &bL[(row - 64) * 128 + col];
          *Lt = (bf16)acc[m][n][j];
        }
    __syncthreads();
#pragma unroll
    for (int it = 0; it < 8; ++it) {
      int row = it * 16 + (tid >> 4);
      int col = (tid & 15) * 8;
      bf16x8 v = (row < 64) ? *(const bf16x8*)&aL[row * 128 + col]
                            : *(const bf16x8*)&bL[(row - 64) * 128 + col];
      *(bf16x8*)&((bf16*)out)[((long)bz << 20) + ((long)(m0 + row) << 10) + n0 + col] = v;
    }
    return;
  }

#pragma unroll
  for (int m = 0; m < 4; ++m) {
#pragma unroll
    for (int n = 0; n < 4; ++n) {
      int ng = n0 + wc * 64 + n * 16 + cl;
      if (ng >= N) continue;
#pragma unroll
      for (int j = 0; j < 4; ++j) {
        int mg = m0 + wr * 64 + m * 16 + rl + j;
        float v = acc[m][n][j];
        if constexpr (MODE == 7) {
          ((float*)out)[((long)bz << 20) + ((long)mg << 10) + ng] =
              __expf(fmaf(v, SCALE, cb2[(bz << 10) + ng]));
        } else if constexpr (MODE == 5) {
          ((bf16*)out)[(long)((bz >> 2) * SEQ + mg) * DM + (bz & 3) * HD + ng] = (bf16)v;
        }
      }
    }
  }
}

// ---------------- layernorm (one wave per row of 768, in place) ----------------
__global__ __launch_bounds__(256) void layernorm_rows(float* x, const float* __restrict__ gam,
                                                      const float* __restrict__ bet) {
  int row = blockIdx.x * 4 + (threadIdx.x >> 6);
  int lane = threadIdx.x & 63;
  float* r = x + (long)row * DM;
  f32x4 v[3];
#pragma unroll
  for (int i = 0; i < 3; ++i) v[i] = *(const f32x4*)&r[i * 256 + lane * 4];
  float s = 0.0f, ss = 0.0f;
#pragma unroll
  for (int i = 0; i < 3; ++i)
#pragma unroll
    for (int j = 0; j < 4; ++j) {
      s += v[i][j];
      ss += v[i][j] * v[i][j];
    }
  for (int d = 1; d < 64; d <<= 1) {
    s += __shfl_xor(s, d);
    ss += __shfl_xor(ss, d);
  }
  float mu = s * (1.0f / 768.0f);
  float var = ss * (1.0f / 768.0f) - mu * mu;
  float rs = 1.0f / sqrtf(var + 1e-5f);
#pragma unroll
  for (int i = 0; i < 3; ++i) {
#pragma unroll
    for (int j = 0; j < 4; ++j) {
      int c = i * 256 + lane * 4 + j;
      v[i][j] = (v[i][j] - mu) * rs * gam[c] + bet[c];
    }
    *(f32x4*)&r[i * 256 + lane * 4] = v[i];
  }
}

// ---------------- launcher ----------------
extern "C" void kernel_launch(void* const* d_in, const int* in_sizes, int n_in,
                              void* d_out, int out_size, void* d_ws, size_t ws_size,
                              hipStream_t stream) {
  const float* Xd = (const float*)d_in[0];
  const float* Xb = (const float*)d_in[1];
  const float* Wq = (const float*)d_in[2];
  const float* bq = (const float*)d_in[3];
  const float* Wk = (const float*)d_in[4];
  const float* bk = (const float*)d_in[5];
  const float* Wv = (const float*)d_in[6];
  const float* bv = (const float*)d_in[7];
  const float* Wb1 = (const float*)d_in[8];
  const float* bb1 = (const float*)d_in[9];
  const float* Wb2 = (const float*)d_in[10];
  const float* bb2 = (const float*)d_in[11];
  const float* Wo = (const float*)d_in[12];
  const float* bo = (const float*)d_in[13];
  const float* lng = (const float*)d_in[14];
  const float* lnb = (const float*)d_in[15];

  float* y = (float*)d_out;                  // 8192*768 f32
  float* attn = y + (long)MROWS * DM;        // 32*1024*1024 f32

  char* w = (char*)d_ws;
  bf16* Xd_bf = (bf16*)w; w += (long)MROWS * DM * 2;   // later reused as ctx
  bf16* Xb_bf = (bf16*)w; w += (long)MROWS * DB * 2;
  bf16* WqvT = (bf16*)w; w += (long)2 * DM * DM * 2;   // [1536][768]
  bf16* WkT = (bf16*)w; w += (long)DM * DB * 2;
  bf16* WoT = (bf16*)w; w += (long)DM * DM * 2;
  bf16* Qb = (bf16*)w; w += (long)MROWS * DM * 2;
  bf16* Kb = (bf16*)w; w += (long)MROWS * DM * 2;
  bf16* VTb = (bf16*)w; w += (long)MROWS * DM * 2;
  float* biasarr = (float*)w; w += (long)BATCH * NHEADS * SEQ * 4;
  float* part = (float*)w; w += (long)32 * SEQ * 16 * 4;   // 2 MB partials
  bf16* Sb = (bf16*)w; w += (long)32 * SEQ * SEQ * 2;      // 64 MB E buffer
  const bool useS = ((size_t)(w - (char*)d_ws)) <= ws_size;
  bf16* ctxb = Xd_bf;  // Xd_bf dead after QV projection; reuse for ctx

  dim3 blk(256);
  // fused prologue: cvt Xd, cvt Xb, bias MLP, tiled weight transposes
  prologue<<<7132, blk, 0, stream>>>(Xd, Xd_bf, Xb, Xb_bf, Wq, Wv, Wk, Wo,
                                     WqvT, WqvT + (long)DM * DM, WkT, WoT,
                                     Wb1, bb1, Wb2, bb2, biasarr);

  // K + [Q|V] projections in one dispatch
  proj_all<<<1152, blk, 0, stream>>>(Xb_bf, WkT, Xd_bf, WqvT, bk, bq, bv, Kb, Qb, VTb);

  if (useS) {
    // E = exp(QK^T*scale + bias) bf16 (staged coalesced) + row-partials
    gemm_bt<2><<<2048, blk, 0, stream>>>(Qb, DM, Kb, DM, nullptr, SEQ, SEQ, HD,
                                         nullptr, biasarr, nullptr, Sb, part);
    // PV: 64x192 blocks, E staged once, attn written in k-loop, ctx staged
    pv_attn<<<512, blk, 0, stream>>>(Sb, VTb, part, ctxb, attn);
  } else {
    gemm_bt<7><<<2048, blk, 0, stream>>>(Qb, DM, Kb, DM, nullptr, SEQ, SEQ, HD,
                                         nullptr, biasarr, nullptr, attn, nullptr);
    rowsum_scale_f32<<<8192, blk, 0, stream>>>(attn);
    gemm_bt<5><<<512, blk, 0, stream>>>(nullptr, SEQ, VTb, SEQ, attn, SEQ, HD, SEQ,
                                        nullptr, nullptr, nullptr, ctxb, nullptr);
  }
  // x = ctx @ Wo + bo + resid -> y region (768 balanced blocks), then LN in place
  final_gemm<<<768, blk, 0, stream>>>(ctxb, WoT, bo, Xd, y);
  layernorm_rows<<<2048, 256, 0, stream>>>(y, lng, lnb);
}